// Round 5
// baseline (267.854 us; speedup 1.0000x reference)
//
#include <hip/hip_runtime.h>

#define N_RAYS   65536
#define N_SAMPLES 128

typedef float f4 __attribute__((ext_vector_type(4)));

// non-temporal 16B ops: evict-first / no-allocate hint down the cache
// hierarchy. grad (100.7MB, zero reuse) is nt-loaded; weight (33.5MB, never
// re-read) is nt-stored. Cacheable working set drops to sdf+z+color+rays
// ~170MB < 256MiB Infinity Cache -> resident across dispatches.
__device__ __forceinline__ f4 ntload4(const float* p) {
    return __builtin_nontemporal_load((const f4*)p);
}
__device__ __forceinline__ void ntstore4(float* p, f4 v) {
    __builtin_nontemporal_store(v, (f4*)p);
}
__device__ __forceinline__ f4 load4(const float* p) {
    return *(const f4*)p;
}

__device__ __forceinline__ float sigmoidf(float x) {
    return 1.0f / (1.0f + __expf(-x));
}

__global__ __launch_bounds__(256) void neus_kernel(
    const float* __restrict__ sdf,
    const float* __restrict__ color,
    const float* __restrict__ z_vals,
    const float* __restrict__ grad_theta,
    const float* __restrict__ rays_d,
    const float* __restrict__ s_ptr,
    const float* __restrict__ car_ptr,
    float* __restrict__ out_pixel,     // [N,3]
    float* __restrict__ out_invdepth,  // [N]
    float* __restrict__ out_weight)    // [N,S]
{
    const int tid = threadIdx.x;
    const int l   = tid & 31;          // lane within ray (owns samples 4l..4l+3)
    const int rl  = tid >> 5;          // ray within block (0..7); 2 rays/wave

    // XCD-aware bijective swizzle (8192 blocks % 8 XCDs == 0): XCD k gets a
    // contiguous 1/8 of the rays -> dense sequential DRAM streams per XCD.
    const int bid = ((int)blockIdx.x & 7) * (N_RAYS / 8 / 8) + ((int)blockIdx.x >> 3);
    const int ray = bid * 8 + rl;

    const size_t base = (size_t)ray * N_SAMPLES;
    const size_t b3   = base * 3 + 12 * l;   // lane's first AoS float (16B-aligned)

    // contiguous 16B/lane loads (resident set)
    const f4 sd = load4(sdf    + base + 4 * l);
    const f4 zz = load4(z_vals + base + 4 * l);

    // grad: NON-TEMPORAL (zero reuse) -> don't pollute L3
    const f4 gA = ntload4(grad_theta + b3);
    const f4 gB = ntload4(grad_theta + b3 + 4);
    const f4 gC = ntload4(grad_theta + b3 + 8);

    // color: regular (stays L3-resident across dispatches)
    const f4 cA = load4(color + b3);
    const f4 cB = load4(color + b3 + 4);
    const f4 cC = load4(color + b3 + 8);

    const float rdx = rays_d[ray * 3 + 0];
    const float rdy = rays_d[ray * 3 + 1];
    const float rdz = rays_d[ray * 3 + 2];
    const float sv  = s_ptr[0];
    const float car = car_ptr[0];
    const float omc = 1.0f - car;

    // true cosine per sample (AoS: g[4l]=(A.x,A.y,A.z), g[4l+1]=(A.w,B.x,B.y),
    //                          g[4l+2]=(B.z,B.w,C.x), g[4l+3]=(C.y,C.z,C.w))
    const float tc0 = rdx * gA.x + rdy * gA.y + rdz * gA.z;
    const float tc1 = rdx * gA.w + rdy * gB.x + rdz * gB.y;
    const float tc2 = rdx * gB.z + rdy * gB.w + rdz * gC.x;
    const float tc3 = rdx * gC.y + rdy * gC.z + rdz * gC.w;

    auto iter_cos = [&](float tc) -> float {
        float a = fmaxf(fmaf(tc, -0.5f, 0.5f), 0.0f);
        float b = fmaxf(-tc, 0.0f);
        return -(a * omc + b * car);
    };
    const float ic0 = iter_cos(tc0);
    const float ic1 = iter_cos(tc1);
    const float ic2 = iter_cos(tc2);
    const float ic3 = iter_cos(tc3);

    // dists: 3 in-register, 1 from neighbor lane (width-32 confined)
    const float zn = __shfl_down(zz.x, 1, 32);   // z[4l+4]; garbage @ l=31 (unused)
    const float d0 = zz.y - zz.x;
    const float d1 = zz.z - zz.y;
    const float d2 = zz.w - zz.z;
    const float d3 = zn   - zz.w;

    auto alpha_f = [&](float sdv, float ic, float d) -> float {
        float h  = ic * d * 0.5f;
        float pc = sigmoidf((sdv - h) * sv);
        float nc = sigmoidf((sdv + h) * sv);
        float a  = (pc - nc + 1e-5f) / (pc + 1e-5f);
        return fminf(fmaxf(a, 0.0f), 1.0f);
    };
    const float a0 = alpha_f(sd.x, ic0, d0);
    const float a1 = alpha_f(sd.y, ic1, d1);
    const float a2 = alpha_f(sd.z, ic2, d2);
    const float a3 = (l == 31) ? 0.0f : alpha_f(sd.w, ic3, d3); // sample 127: zero

    const float om0 = 1.0f - a0;
    const float om1 = 1.0f - a1;
    const float om2 = 1.0f - a2;
    const float om3 = 1.0f - a3;

    // width-32 exclusive product scan (5 steps)
    float scan = om0 * om1 * om2 * om3;
    #pragma unroll
    for (int off = 1; off < 32; off <<= 1) {
        float v = __shfl_up(scan, off, 32);
        if (l >= off) scan *= v;
    }
    float excl = __shfl_up(scan, 1, 32);
    if (l == 0) excl = 1.0f;

    // weights; ref prepends ZERO transmittance at sample 0 -> w[0]=0
    float t  = excl;
    const float w0 = (l == 0) ? 0.0f : t * a0;
    t *= om0; const float w1 = t * a1;
    t *= om1; const float w2 = t * a2;
    t *= om2; const float w3 = t * a3;   // l==31: a3==0 -> 0

    float inv = w0 / zz.x + w1 / zz.y + w2 / zz.z + w3 / zz.w;

    // weight store: NON-TEMPORAL (never re-read) -> no L3 write-allocate churn
    f4 wv; wv.x = w0; wv.y = w1; wv.z = w2; wv.w = w3;
    ntstore4(out_weight + base + 4 * l, wv);

    // pixel partials
    float pr = w0 * cA.x + w1 * cA.w + w2 * cB.z + w3 * cC.y;
    float pg = w0 * cA.y + w1 * cB.x + w2 * cB.w + w3 * cC.z;
    float pb = w0 * cA.z + w1 * cB.y + w2 * cC.x + w3 * cC.w;

    // width-32 butterfly reduction (5 steps x 4 values)
    #pragma unroll
    for (int off = 16; off > 0; off >>= 1) {
        pr  += __shfl_xor(pr,  off, 32);
        pg  += __shfl_xor(pg,  off, 32);
        pb  += __shfl_xor(pb,  off, 32);
        inv += __shfl_xor(inv, off, 32);
    }

    if (l == 0) {
        out_pixel[ray * 3 + 0] = pr;
        out_pixel[ray * 3 + 1] = pg;
        out_pixel[ray * 3 + 2] = pb;
        out_invdepth[ray]      = inv;
    }
}

extern "C" void kernel_launch(void* const* d_in, const int* in_sizes, int n_in,
                              void* d_out, int out_size, void* d_ws, size_t ws_size,
                              hipStream_t stream) {
    const float* sdf        = (const float*)d_in[0];
    const float* color      = (const float*)d_in[1];
    const float* z_vals     = (const float*)d_in[2];
    const float* grad_theta = (const float*)d_in[3];
    const float* rays_d     = (const float*)d_in[4];
    const float* s_ptr      = (const float*)d_in[5];
    const float* car_ptr    = (const float*)d_in[6];

    float* out          = (float*)d_out;
    float* out_pixel    = out;                        // N*3
    float* out_invdepth = out + (size_t)N_RAYS * 3;   // N
    float* out_weight   = out + (size_t)N_RAYS * 4;   // N*S

    dim3 block(256);                 // 4 waves = 8 rays per block
    dim3 grid(N_RAYS / 8);           // 8192 blocks

    neus_kernel<<<grid, block, 0, stream>>>(
        sdf, color, z_vals, grad_theta, rays_d, s_ptr, car_ptr,
        out_pixel, out_invdepth, out_weight);
}